// Round 3
// baseline (169.865 us; speedup 1.0000x reference)
//
#include <hip/hip_runtime.h>
#include <stdint.h>

#define N_NODES 50000
#define N_EDGES 800000
#define IN_F 128
#define HEADS 8
#define HEAD_DIM 16
#define ALPHA 0.2f
#define EPSV 1e-6f

#define NB 196          // buckets = tgt >> 8
#define CAP 4800        // per-bucket capacity (mean 4096, sigma ~64 -> 11 sigma)

typedef short short8 __attribute__((ext_vector_type(8)));
typedef float floatx4 __attribute__((ext_vector_type(4)));

__device__ __forceinline__ float bflo(unsigned v) {
    return __uint_as_float(v << 16);
}
__device__ __forceinline__ float bfhi(unsigned v) {
    return __uint_as_float(v & 0xffff0000u);
}
__device__ __forceinline__ unsigned f2bf(float f) {
    unsigned u = __float_as_uint(f);
    return (u + 0x7fffu + ((u >> 16) & 1u)) >> 16;
}

// ---------------- k_front: passA split to 782 blocks (1024 edges each, was
// 391x2048 -> 1.5 waves/SIMD latency-starved standalone) + 1 block doing the
// W transpose (k_wt folded in; gcnt zeroing moved to hipMemsetAsync).
__global__ __launch_bounds__(256) void k_front(const int* __restrict__ srcA,
                                               const int* __restrict__ tgtA,
                                               int* __restrict__ gcnt,
                                               unsigned* __restrict__ bucketbuf,
                                               const float* __restrict__ W,
                                               ushort* __restrict__ WTb) {
    int b = blockIdx.x, t = threadIdx.x;
    if (b == 782) {
        // ---- W[h][f][d] fp32 -> WTb[c][f] bf16
        for (int i = t; i < 16384; i += 256) {
            int c = i >> 7, f = i & 127;
            WTb[i] = (ushort)f2bf(W[(c >> 4) * 2048 + f * 16 + (c & 15)]);
        }
        return;
    }
    // ---- passA body: 1024 edges per block; 782*1024 = 800768 >= 800000
    __shared__ int lcnt[NB];
    __shared__ int lbase[NB];
    if (t < NB) lcnt[t] = 0;
    __syncthreads();

    int base = b * 1024 + t;
    int tg[4], sr[4];
    bool vld[4];
#pragma unroll
    for (int k = 0; k < 4; k++) {
        int e = base + k * 256;
        vld[k] = (e < N_EDGES);
        int ee = vld[k] ? e : 0;
        tg[k] = tgtA[ee];
        sr[k] = srcA[ee];
    }
#pragma unroll
    for (int k = 0; k < 4; k++)
        if (vld[k]) atomicAdd(&lcnt[tg[k] >> 8], 1);
    __syncthreads();
    if (t < NB) {
        int c = lcnt[t];
        lbase[t] = (c > 0) ? atomicAdd(&gcnt[t], c) : 0;
        lcnt[t] = 0;
    }
    __syncthreads();
#pragma unroll
    for (int k = 0; k < 4; k++) {
        if (vld[k]) {
            int bb = tg[k] >> 8;
            int off = atomicAdd(&lcnt[bb], 1);
            int pos = lbase[bb] + off;
            if (pos < CAP)
                bucketbuf[(size_t)bb * CAP + pos] =
                    ((unsigned)(tg[k] & 255) << 16) | (unsigned)sr[k];
        }
    }
}

// ---------------- k_mid2: fusion of k1_mfma (782 blocks) and passB (196).
// passB only depends on passA (previous kernel); k1 only on WTb (also previous
// kernel). Complementary pipes (MFMA/VALU vs LDS-sort/atomics); 4:1 interleave
// keeps both co-resident so passB's ~10us hides under k1.
__global__ __launch_bounds__(256) void k_mid2(const float* __restrict__ x,
                                              const ushort* __restrict__ WTb,
                                              const float* __restrict__ a,
                                              ushort* __restrict__ hb,
                                              float* __restrict__ s_src,
                                              float* __restrict__ s_tgt,
                                              const unsigned* __restrict__ bucketbuf,
                                              const int* __restrict__ gcnt,
                                              int* __restrict__ rowptr,
                                              ushort* __restrict__ src16) {
    int bi = blockIdx.x;        // grid = 980 = 196*5 ; r<4 -> mfma, r==4 -> passB
    int q = bi / 5, r = bi - q * 5;
    int t = threadIdx.x, lane = t & 63, w = t >> 6;

    if (r == 4) {
        // ---------------- passB body (b = q in [0,196))
        __shared__ int bin[256];
        __shared__ int wsum[4];
        __shared__ int woff[4];
        __shared__ int sbase;
        __shared__ ushort stage[CAP];
        int b = q;

        // inline exclusive scan of gcnt[0..NB)
        bin[t] = 0;
        int g = (t < NB) ? gcnt[t] : 0;
        int incg = g;
#pragma unroll
        for (int off = 1; off < 64; off <<= 1) {
            int nn = __shfl_up(incg, off, 64);
            if (lane >= off) incg += nn;
        }
        if (lane == 63) wsum[w] = incg;
        __syncthreads();
        if (t == 0) {
            woff[0] = 0;
            woff[1] = wsum[0];
            woff[2] = wsum[0] + wsum[1];
            woff[3] = wsum[0] + wsum[1] + wsum[2];
        }
        __syncthreads();
        if (t == b) sbase = woff[w] + incg - g;   // b < NB <= 256
        if (b == 0 && t == 0) rowptr[N_NODES] = N_EDGES;
        __syncthreads();
        int base = sbase;
        int n = gcnt[b]; if (n > CAP) n = CAP;
        const unsigned* buf = bucketbuf + (size_t)b * CAP;

        for (int i = t; i < n; i += 256)
            atomicAdd(&bin[buf[i] >> 16], 1);
        __syncthreads();
        int v = bin[t];
        int inc = v;
#pragma unroll
        for (int off = 1; off < 64; off <<= 1) {
            int nn = __shfl_up(inc, off, 64);
            if (lane >= off) inc += nn;
        }
        if (lane == 63) wsum[w] = inc;
        __syncthreads();
        if (t == 0) {
            woff[0] = 0;
            woff[1] = wsum[0];
            woff[2] = wsum[0] + wsum[1];
            woff[3] = wsum[0] + wsum[1] + wsum[2];
        }
        __syncthreads();
        int excl = woff[w] + inc - v;
        int node = b * 256 + t;
        if (node < N_NODES) rowptr[node] = base + excl;
        __syncthreads();
        bin[t] = excl;
        __syncthreads();
        for (int i = t; i < n; i += 256) {
            unsigned p = buf[i];
            int off = atomicAdd(&bin[p >> 16], 1);
            stage[off] = (ushort)(p & 0xffffu);
        }
        __syncthreads();
        for (int i = t; i < n; i += 256)
            src16[base + i] = stage[i];
        return;
    }

    // ---------------- k1_mfma body (mb = q*4 + r in [0,784); 782,783 empty)
    int mb = q * 4 + r;
    int wave = w;
    int quad = lane >> 4, col = lane & 15;
    int nb = mb * 64 + wave * 16;
    if (mb * 64 >= N_NODES) return;

    int na = nb + col;
    int nac = na < N_NODES ? na : (N_NODES - 1);
    const float* xrow = x + (size_t)nac * 128 + quad * 8;

    floatx4 acc[8];
    floatx4 z = {0.f, 0.f, 0.f, 0.f};
#pragma unroll
    for (int ct = 0; ct < 8; ct++) acc[ct] = z;

#pragma unroll
    for (int kc = 0; kc < 4; kc++) {
        float4 f0 = *(const float4*)(xrow + kc * 32);
        float4 f1 = *(const float4*)(xrow + kc * 32 + 4);
        short8 af;
        af[0] = (short)f2bf(f0.x); af[1] = (short)f2bf(f0.y);
        af[2] = (short)f2bf(f0.z); af[3] = (short)f2bf(f0.w);
        af[4] = (short)f2bf(f1.x); af[5] = (short)f2bf(f1.y);
        af[6] = (short)f2bf(f1.z); af[7] = (short)f2bf(f1.w);
#pragma unroll
        for (int ct = 0; ct < 8; ct++) {
            const ushort* wrow = WTb + (size_t)(ct * 16 + col) * 128 + kc * 32 + quad * 8;
            short8 bf = *(const short8*)wrow;
            acc[ct] = __builtin_amdgcn_mfma_f32_16x16x32_bf16(af, bf, acc[ct], 0, 0, 0);
        }
    }

    float af_s[8], af_t[8];
#pragma unroll
    for (int ct = 0; ct < 8; ct++) {
        af_s[ct] = a[ct * 32 + col];
        af_t[ct] = a[ct * 32 + 16 + col];
    }

#pragma unroll
    for (int rr = 0; rr < 4; rr++) {
        int node = nb + quad * 4 + rr;
        bool nv = (node < N_NODES);
        if (nv) {
            ushort* hrow = hb + (size_t)node * 128 + col;
#pragma unroll
            for (int ct = 0; ct < 8; ct++)
                hrow[ct * 16] = (ushort)f2bf(acc[ct][rr]);
        }
        float ps[8], pt[8];
#pragma unroll
        for (int ct = 0; ct < 8; ct++) {
            float hs = acc[ct][rr];
            float vs = hs * af_s[ct];
            float vt = hs * af_t[ct];
#pragma unroll
            for (int off = 1; off < 16; off <<= 1) {
                vs += __shfl_xor(vs, off, 64);
                vt += __shfl_xor(vt, off, 64);
            }
            ps[ct] = vs; pt[ct] = vt;
        }
        if (nv && col == 0) {
            *(float4*)(s_src + (size_t)node * 8)     = make_float4(ps[0], ps[1], ps[2], ps[3]);
            *(float4*)(s_src + (size_t)node * 8 + 4) = make_float4(ps[4], ps[5], ps[6], ps[7]);
            *(float4*)(s_tgt + (size_t)node * 8)     = make_float4(pt[0], pt[1], pt[2], pt[3]);
            *(float4*)(s_tgt + (size_t)node * 8 + 4) = make_float4(pt[4], pt[5], pt[6], pt[7]);
        }
    }
}

// ---------------- fused: TWO nodes per wave (32 lanes each); src16 index.
// 8-edge window (verified R2). Max-shift removed (cancels in normalization).
__global__ __launch_bounds__(256) void k_fused(const int* __restrict__ rowptr,
                                               const ushort* __restrict__ src16,
                                               const float* __restrict__ s_src,
                                               const float* __restrict__ s_tgt,
                                               const unsigned* __restrict__ h16,
                                               const float* __restrict__ bias,
                                               float* __restrict__ outb) {
    int t = threadIdx.x;
    int wave = t >> 6, lane = t & 63;
    int half = lane >> 5, hl = lane & 31;
    int n = blockIdx.x * 8 + wave * 2 + half;   // 6250*8 == 50000
    int head = hl >> 2;
    int c = 4 * hl;

    const uint2* h2 = (const uint2*)h16;

    float st = s_tgt[n * 8 + head];
    int begin = rowptr[n], end = rowptr[n + 1];

    float ax = 0.f, ay = 0.f, az = 0.f, aw = 0.f, den = 0.f;
    int e = begin;
    for (; e + 7 < end; e += 8) {
        int s0 = src16[e];
        int s1 = src16[e + 1];
        int s2 = src16[e + 2];
        int s3 = src16[e + 3];
        int s4 = src16[e + 4];
        int s5 = src16[e + 5];
        int s6 = src16[e + 6];
        int s7 = src16[e + 7];
        float t0 = s_src[s0 * 8 + head];
        float t1 = s_src[s1 * 8 + head];
        float t2 = s_src[s2 * 8 + head];
        float t3 = s_src[s3 * 8 + head];
        float t4 = s_src[s4 * 8 + head];
        float t5 = s_src[s5 * 8 + head];
        float t6 = s_src[s6 * 8 + head];
        float t7 = s_src[s7 * 8 + head];
        uint2 p0 = h2[s0 * 32 + hl];
        uint2 p1 = h2[s1 * 32 + hl];
        uint2 p2 = h2[s2 * 32 + hl];
        uint2 p3 = h2[s3 * 32 + hl];
        uint2 p4 = h2[s4 * 32 + hl];
        uint2 p5 = h2[s5 * 32 + hl];
        uint2 p6 = h2[s6 * 32 + hl];
        uint2 p7 = h2[s7 * 32 + hl];
        float v0 = t0 + st; v0 = v0 >= 0.f ? v0 : ALPHA * v0;
        float v1 = t1 + st; v1 = v1 >= 0.f ? v1 : ALPHA * v1;
        float v2 = t2 + st; v2 = v2 >= 0.f ? v2 : ALPHA * v2;
        float v3 = t3 + st; v3 = v3 >= 0.f ? v3 : ALPHA * v3;
        float v4 = t4 + st; v4 = v4 >= 0.f ? v4 : ALPHA * v4;
        float v5 = t5 + st; v5 = v5 >= 0.f ? v5 : ALPHA * v5;
        float v6 = t6 + st; v6 = v6 >= 0.f ? v6 : ALPHA * v6;
        float v7 = t7 + st; v7 = v7 >= 0.f ? v7 : ALPHA * v7;
        float x0 = __expf(fminf(fmaxf(v0, -20.f), 20.f));
        float x1 = __expf(fminf(fmaxf(v1, -20.f), 20.f));
        float x2 = __expf(fminf(fmaxf(v2, -20.f), 20.f));
        float x3 = __expf(fminf(fmaxf(v3, -20.f), 20.f));
        float x4 = __expf(fminf(fmaxf(v4, -20.f), 20.f));
        float x5 = __expf(fminf(fmaxf(v5, -20.f), 20.f));
        float x6 = __expf(fminf(fmaxf(v6, -20.f), 20.f));
        float x7 = __expf(fminf(fmaxf(v7, -20.f), 20.f));
        den += ((x0 + x1) + (x2 + x3)) + ((x4 + x5) + (x6 + x7));
        ax = fmaf(x0, bflo(p0.x), fmaf(x1, bflo(p1.x), fmaf(x2, bflo(p2.x), fmaf(x3, bflo(p3.x), ax))));
        ax = fmaf(x4, bflo(p4.x), fmaf(x5, bflo(p5.x), fmaf(x6, bflo(p6.x), fmaf(x7, bflo(p7.x), ax))));
        ay = fmaf(x0, bfhi(p0.x), fmaf(x1, bfhi(p1.x), fmaf(x2, bfhi(p2.x), fmaf(x3, bfhi(p3.x), ay))));
        ay = fmaf(x4, bfhi(p4.x), fmaf(x5, bfhi(p5.x), fmaf(x6, bfhi(p6.x), fmaf(x7, bfhi(p7.x), ay))));
        az = fmaf(x0, bflo(p0.y), fmaf(x1, bflo(p1.y), fmaf(x2, bflo(p2.y), fmaf(x3, bflo(p3.y), az))));
        az = fmaf(x4, bflo(p4.y), fmaf(x5, bflo(p5.y), fmaf(x6, bflo(p6.y), fmaf(x7, bflo(p7.y), az))));
        aw = fmaf(x0, bfhi(p0.y), fmaf(x1, bfhi(p1.y), fmaf(x2, bfhi(p2.y), fmaf(x3, bfhi(p3.y), aw))));
        aw = fmaf(x4, bfhi(p4.y), fmaf(x5, bfhi(p5.y), fmaf(x6, bfhi(p6.y), fmaf(x7, bfhi(p7.y), aw))));
    }
    if (e + 3 < end) {
        int s0 = src16[e];
        int s1 = src16[e + 1];
        int s2 = src16[e + 2];
        int s3 = src16[e + 3];
        float t0 = s_src[s0 * 8 + head];
        float t1 = s_src[s1 * 8 + head];
        float t2 = s_src[s2 * 8 + head];
        float t3 = s_src[s3 * 8 + head];
        uint2 p0 = h2[s0 * 32 + hl];
        uint2 p1 = h2[s1 * 32 + hl];
        uint2 p2 = h2[s2 * 32 + hl];
        uint2 p3 = h2[s3 * 32 + hl];
        float v0 = t0 + st; v0 = v0 >= 0.f ? v0 : ALPHA * v0;
        float v1 = t1 + st; v1 = v1 >= 0.f ? v1 : ALPHA * v1;
        float v2 = t2 + st; v2 = v2 >= 0.f ? v2 : ALPHA * v2;
        float v3 = t3 + st; v3 = v3 >= 0.f ? v3 : ALPHA * v3;
        float x0 = __expf(fminf(fmaxf(v0, -20.f), 20.f));
        float x1 = __expf(fminf(fmaxf(v1, -20.f), 20.f));
        float x2 = __expf(fminf(fmaxf(v2, -20.f), 20.f));
        float x3 = __expf(fminf(fmaxf(v3, -20.f), 20.f));
        den += (x0 + x1) + (x2 + x3);
        ax = fmaf(x0, bflo(p0.x), fmaf(x1, bflo(p1.x), fmaf(x2, bflo(p2.x), fmaf(x3, bflo(p3.x), ax))));
        ay = fmaf(x0, bfhi(p0.x), fmaf(x1, bfhi(p1.x), fmaf(x2, bfhi(p2.x), fmaf(x3, bfhi(p3.x), ay))));
        az = fmaf(x0, bflo(p0.y), fmaf(x1, bflo(p1.y), fmaf(x2, bflo(p2.y), fmaf(x3, bflo(p3.y), az))));
        aw = fmaf(x0, bfhi(p0.y), fmaf(x1, bfhi(p1.y), fmaf(x2, bfhi(p2.y), fmaf(x3, bfhi(p3.y), aw))));
        e += 4;
    }
    for (; e < end; e++) {
        int sA = src16[e];
        float ssA = s_src[sA * 8 + head];
        uint2 pA = h2[sA * 32 + hl];
        float vA = ssA + st; vA = vA >= 0.f ? vA : ALPHA * vA;
        float exA = __expf(fminf(fmaxf(vA, -20.f), 20.f));
        den += exA;
        ax = fmaf(exA, bflo(pA.x), ax);
        ay = fmaf(exA, bfhi(pA.x), ay);
        az = fmaf(exA, bflo(pA.y), az);
        aw = fmaf(exA, bfhi(pA.y), aw);
    }
    float r = 1.f / (den + EPSV);
    float4 b = *(const float4*)(bias + c);
    float4 o;
    o.x = fmaf(ax, r, b.x);
    o.y = fmaf(ay, r, b.y);
    o.z = fmaf(az, r, b.z);
    o.w = fmaf(aw, r, b.w);
    *(float4*)(outb + (size_t)n * 128 + c) = o;
}

extern "C" void kernel_launch(void* const* d_in, const int* in_sizes, int n_in,
                              void* d_out, int out_size, void* d_ws, size_t ws_size,
                              hipStream_t stream) {
    const float* x    = (const float*)d_in[0];
    const int*   ei   = (const int*)d_in[1];
    const float* W    = (const float*)d_in[2];
    const float* a    = (const float*)d_in[3];
    const float* bias = (const float*)d_in[4];
    float* outb = (float*)d_out;

    char* ws = (char*)d_ws;
    // layout (bytes):
    ushort* hb        = (ushort*)(ws);                   // 12,800,000
    float* s_src      = (float*)(ws + 12800000);         //  1,600,000
    float* s_tgt      = (float*)(ws + 14400000);         //  1,600,000
    int*   rowptr     = (int*)  (ws + 16000000);         //    200,064
    ushort* src16     = (ushort*)(ws + 16200064);        //  1,600,000
    int*   gcnt       = (int*)  (ws + 17800064);         //      1,024
    ushort* WTb       = (ushort*)(ws + 17902528);        //     32,768
    unsigned* bucketbuf = (unsigned*)(ws + 17935296);    //  3,763,200

    const int* srcA = ei;
    const int* tgtA = ei + N_EDGES;

    hipMemsetAsync(gcnt, 0, NB * sizeof(int), stream);
    hipLaunchKernelGGL(k_front, dim3(783),  dim3(256), 0, stream, srcA, tgtA, gcnt, bucketbuf, W, WTb);
    hipLaunchKernelGGL(k_mid2,  dim3(980),  dim3(256), 0, stream,
                       x, WTb, a, hb, s_src, s_tgt, bucketbuf, gcnt, rowptr, src16);
    hipLaunchKernelGGL(k_fused, dim3(6250), dim3(256), 0, stream, rowptr, src16, s_src, s_tgt, (const unsigned*)hb, bias, outb);
}

// Round 4
// 153.313 us; speedup vs baseline: 1.1080x; 1.1080x over previous
//
#include <hip/hip_runtime.h>
#include <stdint.h>

#define N_NODES 50000
#define N_EDGES 800000
#define IN_F 128
#define HEADS 8
#define HEAD_DIM 16
#define ALPHA 0.2f
#define EPSV 1e-6f

#define NB 196          // buckets = tgt >> 8
#define CAP 4800        // per-bucket capacity (mean 4096, sigma ~64 -> 11 sigma)

typedef short short8 __attribute__((ext_vector_type(8)));
typedef float floatx4 __attribute__((ext_vector_type(4)));

__device__ __forceinline__ float bflo(unsigned v) {
    return __uint_as_float(v << 16);
}
__device__ __forceinline__ float bfhi(unsigned v) {
    return __uint_as_float(v & 0xffff0000u);
}
__device__ __forceinline__ unsigned f2bf(float f) {
    unsigned u = __float_as_uint(f);
    return (u + 0x7fffu + ((u >> 16) & 1u)) >> 16;
}

// ---------------- wt: W[h][f][d] fp32 -> WTb[c][f] bf16 ; zero gcnt
__global__ __launch_bounds__(256) void k_wt(const float* __restrict__ W,
                                            ushort* __restrict__ WTb,
                                            int* __restrict__ gcnt) {
    int i = blockIdx.x * 256 + threadIdx.x;   // 64*256 = 16384
    int c = i >> 7, f = i & 127;
    WTb[i] = (ushort)f2bf(W[(c >> 4) * 2048 + f * 16 + (c & 15)]);
    if (i < NB) gcnt[i] = 0;
}

// ---------------- k_mid: fusion of k1_mfma (782 blocks) and passA (391 blocks).
// VERIFIED R2 structure (156.6us). passA rides co-resident with the MFMA
// blocks (complementary pipes); do NOT re-serialize this overlap (R3 lesson).
__global__ __launch_bounds__(256) void k_mid(const float* __restrict__ x,
                                             const ushort* __restrict__ WTb,
                                             const float* __restrict__ a,
                                             ushort* __restrict__ hb,
                                             float* __restrict__ s_src,
                                             float* __restrict__ s_tgt,
                                             const int* __restrict__ srcA,
                                             const int* __restrict__ tgtA,
                                             int* __restrict__ gcnt,
                                             unsigned* __restrict__ bucketbuf) {
    int bi = blockIdx.x;        // grid = 1173 = 3*391; 782 mfma + 391 passA
    int q3 = bi / 3, r3 = bi - q3 * 3;
    int t = threadIdx.x;

    if (r3 == 2) {
        // ---------------- passA body (b = q3 in [0,391))
        __shared__ int lcnt[NB];
        __shared__ int lbase[NB];
        if (t < NB) lcnt[t] = 0;
        __syncthreads();

        int base = q3 * 2048 + t;   // 391 blocks * 2048 = 800768
        int tg[8], sr[8];
        bool vld[8];
#pragma unroll
        for (int k = 0; k < 8; k++) {
            int e = base + k * 256;
            vld[k] = (e < N_EDGES);
            int ee = vld[k] ? e : 0;
            tg[k] = tgtA[ee];
            sr[k] = srcA[ee];
        }
#pragma unroll
        for (int k = 0; k < 8; k++)
            if (vld[k]) atomicAdd(&lcnt[tg[k] >> 8], 1);
        __syncthreads();
        if (t < NB) {
            int c = lcnt[t];
            lbase[t] = (c > 0) ? atomicAdd(&gcnt[t], c) : 0;
            lcnt[t] = 0;
        }
        __syncthreads();
#pragma unroll
        for (int k = 0; k < 8; k++) {
            if (vld[k]) {
                int b = tg[k] >> 8;
                int off = atomicAdd(&lcnt[b], 1);
                int pos = lbase[b] + off;
                if (pos < CAP)
                    bucketbuf[(size_t)b * CAP + pos] =
                        ((unsigned)(tg[k] & 255) << 16) | (unsigned)sr[k];
            }
        }
        return;
    }

    // ---------------- k1_mfma body (mb = q3*2 + r3 in [0,782))
    int mb = q3 * 2 + r3;
    int wave = t >> 6, lane = t & 63;
    int quad = lane >> 4, col = lane & 15;
    int nb = mb * 64 + wave * 16;             // up to 50047 >= 50000

    int na = nb + col;
    int nac = na < N_NODES ? na : (N_NODES - 1);
    const float* xrow = x + (size_t)nac * 128 + quad * 8;

    floatx4 acc[8];
    floatx4 z = {0.f, 0.f, 0.f, 0.f};
#pragma unroll
    for (int ct = 0; ct < 8; ct++) acc[ct] = z;

#pragma unroll
    for (int kc = 0; kc < 4; kc++) {
        float4 f0 = *(const float4*)(xrow + kc * 32);
        float4 f1 = *(const float4*)(xrow + kc * 32 + 4);
        short8 af;
        af[0] = (short)f2bf(f0.x); af[1] = (short)f2bf(f0.y);
        af[2] = (short)f2bf(f0.z); af[3] = (short)f2bf(f0.w);
        af[4] = (short)f2bf(f1.x); af[5] = (short)f2bf(f1.y);
        af[6] = (short)f2bf(f1.z); af[7] = (short)f2bf(f1.w);
#pragma unroll
        for (int ct = 0; ct < 8; ct++) {
            const ushort* wrow = WTb + (size_t)(ct * 16 + col) * 128 + kc * 32 + quad * 8;
            short8 bf = *(const short8*)wrow;
            acc[ct] = __builtin_amdgcn_mfma_f32_16x16x32_bf16(af, bf, acc[ct], 0, 0, 0);
        }
    }

    float af_s[8], af_t[8];
#pragma unroll
    for (int ct = 0; ct < 8; ct++) {
        af_s[ct] = a[ct * 32 + col];
        af_t[ct] = a[ct * 32 + 16 + col];
    }

#pragma unroll
    for (int r = 0; r < 4; r++) {
        int node = nb + quad * 4 + r;
        bool nv = (node < N_NODES);
        if (nv) {
            ushort* hrow = hb + (size_t)node * 128 + col;
#pragma unroll
            for (int ct = 0; ct < 8; ct++)
                hrow[ct * 16] = (ushort)f2bf(acc[ct][r]);
        }
        float ps[8], pt[8];
#pragma unroll
        for (int ct = 0; ct < 8; ct++) {
            float hs = acc[ct][r];
            float vs = hs * af_s[ct];
            float vt = hs * af_t[ct];
#pragma unroll
            for (int off = 1; off < 16; off <<= 1) {
                vs += __shfl_xor(vs, off, 64);
                vt += __shfl_xor(vt, off, 64);
            }
            ps[ct] = vs; pt[ct] = vt;
        }
        if (nv && col == 0) {
            *(float4*)(s_src + (size_t)node * 8)     = make_float4(ps[0], ps[1], ps[2], ps[3]);
            *(float4*)(s_src + (size_t)node * 8 + 4) = make_float4(ps[4], ps[5], ps[6], ps[7]);
            *(float4*)(s_tgt + (size_t)node * 8)     = make_float4(pt[0], pt[1], pt[2], pt[3]);
            *(float4*)(s_tgt + (size_t)node * 8 + 4) = make_float4(pt[4], pt[5], pt[6], pt[7]);
        }
    }
}

// ---------------- passB: 512 threads (was 256). The kernel is the only fully
// exposed stage in the R2 pipeline and is latency-bound at 196 blocks; doubling
// threads halves every strided pass (count/scatter/copy). Scan portions run in
// the first 256 threads (4 waves), unchanged logic.
__global__ __launch_bounds__(512) void k_passB(const unsigned* __restrict__ bucketbuf,
                                               const int* __restrict__ gcnt,
                                               int* __restrict__ rowptr,
                                               ushort* __restrict__ src16) {
    __shared__ int bin[256];
    __shared__ int wsum[4];
    __shared__ int woff[4];
    __shared__ int sbase;
    __shared__ ushort stage[CAP];
    int t = threadIdx.x, lane = t & 63, w = t >> 6;
    int b = blockIdx.x;

    if (t < 256) bin[t] = 0;

    // --- inline exclusive scan of gcnt[0..NB) (threads 0..255 only)
    int g = (t < NB) ? gcnt[t] : 0;
    int incg = g;
#pragma unroll
    for (int off = 1; off < 64; off <<= 1) {
        int nn = __shfl_up(incg, off, 64);
        if (lane >= off) incg += nn;
    }
    if (t < 256 && lane == 63) wsum[w] = incg;
    __syncthreads();
    if (t == 0) {
        woff[0] = 0;
        woff[1] = wsum[0];
        woff[2] = wsum[0] + wsum[1];
        woff[3] = wsum[0] + wsum[1] + wsum[2];
    }
    __syncthreads();
    if (t == b) sbase = woff[w] + incg - g;   // b < NB <= 256
    if (b == 0 && t == 0) rowptr[N_NODES] = N_EDGES;
    __syncthreads();
    int base = sbase;
    int n = gcnt[b]; if (n > CAP) n = CAP;
    const unsigned* buf = bucketbuf + (size_t)b * CAP;

    // --- count local tgt bins (all 512 threads)
    for (int i = t; i < n; i += 512)
        atomicAdd(&bin[buf[i] >> 16], 1);
    __syncthreads();
    // --- exclusive scan over 256 bins (threads 0..255)
    int v = (t < 256) ? bin[t] : 0;
    int inc = v;
#pragma unroll
    for (int off = 1; off < 64; off <<= 1) {
        int nn = __shfl_up(inc, off, 64);
        if (lane >= off) inc += nn;
    }
    if (t < 256 && lane == 63) wsum[w] = inc;
    __syncthreads();
    if (t == 0) {
        woff[0] = 0;
        woff[1] = wsum[0];
        woff[2] = wsum[0] + wsum[1];
        woff[3] = wsum[0] + wsum[1] + wsum[2];
    }
    __syncthreads();
    if (t < 256) {
        int excl = woff[w] + inc - v;
        int node = b * 256 + t;
        if (node < N_NODES) rowptr[node] = base + excl;
        __syncthreads();          // matched below for t>=256
        bin[t] = excl;            // reuse as scatter cursor
    } else {
        __syncthreads();
    }
    __syncthreads();
    for (int i = t; i < n; i += 512) {
        unsigned p = buf[i];
        int off = atomicAdd(&bin[p >> 16], 1);
        stage[off] = (ushort)(p & 0xffffu);
    }
    __syncthreads();
    for (int i = t; i < n; i += 512)
        src16[base + i] = stage[i];
}

// ---------------- fused: TWO nodes per wave (32 lanes each); src16 index.
// 8-edge window (verified R2). Max-shift removed (cancels in normalization).
__global__ __launch_bounds__(256) void k_fused(const int* __restrict__ rowptr,
                                               const ushort* __restrict__ src16,
                                               const float* __restrict__ s_src,
                                               const float* __restrict__ s_tgt,
                                               const unsigned* __restrict__ h16,
                                               const float* __restrict__ bias,
                                               float* __restrict__ outb) {
    int t = threadIdx.x;
    int wave = t >> 6, lane = t & 63;
    int half = lane >> 5, hl = lane & 31;
    int n = blockIdx.x * 8 + wave * 2 + half;   // 6250*8 == 50000
    int head = hl >> 2;
    int c = 4 * hl;

    const uint2* h2 = (const uint2*)h16;

    float st = s_tgt[n * 8 + head];
    int begin = rowptr[n], end = rowptr[n + 1];

    float ax = 0.f, ay = 0.f, az = 0.f, aw = 0.f, den = 0.f;
    int e = begin;
    for (; e + 7 < end; e += 8) {
        int s0 = src16[e];
        int s1 = src16[e + 1];
        int s2 = src16[e + 2];
        int s3 = src16[e + 3];
        int s4 = src16[e + 4];
        int s5 = src16[e + 5];
        int s6 = src16[e + 6];
        int s7 = src16[e + 7];
        float t0 = s_src[s0 * 8 + head];
        float t1 = s_src[s1 * 8 + head];
        float t2 = s_src[s2 * 8 + head];
        float t3 = s_src[s3 * 8 + head];
        float t4 = s_src[s4 * 8 + head];
        float t5 = s_src[s5 * 8 + head];
        float t6 = s_src[s6 * 8 + head];
        float t7 = s_src[s7 * 8 + head];
        uint2 p0 = h2[s0 * 32 + hl];
        uint2 p1 = h2[s1 * 32 + hl];
        uint2 p2 = h2[s2 * 32 + hl];
        uint2 p3 = h2[s3 * 32 + hl];
        uint2 p4 = h2[s4 * 32 + hl];
        uint2 p5 = h2[s5 * 32 + hl];
        uint2 p6 = h2[s6 * 32 + hl];
        uint2 p7 = h2[s7 * 32 + hl];
        float v0 = t0 + st; v0 = v0 >= 0.f ? v0 : ALPHA * v0;
        float v1 = t1 + st; v1 = v1 >= 0.f ? v1 : ALPHA * v1;
        float v2 = t2 + st; v2 = v2 >= 0.f ? v2 : ALPHA * v2;
        float v3 = t3 + st; v3 = v3 >= 0.f ? v3 : ALPHA * v3;
        float v4 = t4 + st; v4 = v4 >= 0.f ? v4 : ALPHA * v4;
        float v5 = t5 + st; v5 = v5 >= 0.f ? v5 : ALPHA * v5;
        float v6 = t6 + st; v6 = v6 >= 0.f ? v6 : ALPHA * v6;
        float v7 = t7 + st; v7 = v7 >= 0.f ? v7 : ALPHA * v7;
        float x0 = __expf(fminf(fmaxf(v0, -20.f), 20.f));
        float x1 = __expf(fminf(fmaxf(v1, -20.f), 20.f));
        float x2 = __expf(fminf(fmaxf(v2, -20.f), 20.f));
        float x3 = __expf(fminf(fmaxf(v3, -20.f), 20.f));
        float x4 = __expf(fminf(fmaxf(v4, -20.f), 20.f));
        float x5 = __expf(fminf(fmaxf(v5, -20.f), 20.f));
        float x6 = __expf(fminf(fmaxf(v6, -20.f), 20.f));
        float x7 = __expf(fminf(fmaxf(v7, -20.f), 20.f));
        den += ((x0 + x1) + (x2 + x3)) + ((x4 + x5) + (x6 + x7));
        ax = fmaf(x0, bflo(p0.x), fmaf(x1, bflo(p1.x), fmaf(x2, bflo(p2.x), fmaf(x3, bflo(p3.x), ax))));
        ax = fmaf(x4, bflo(p4.x), fmaf(x5, bflo(p5.x), fmaf(x6, bflo(p6.x), fmaf(x7, bflo(p7.x), ax))));
        ay = fmaf(x0, bfhi(p0.x), fmaf(x1, bfhi(p1.x), fmaf(x2, bfhi(p2.x), fmaf(x3, bfhi(p3.x), ay))));
        ay = fmaf(x4, bfhi(p4.x), fmaf(x5, bfhi(p5.x), fmaf(x6, bfhi(p6.x), fmaf(x7, bfhi(p7.x), ay))));
        az = fmaf(x0, bflo(p0.y), fmaf(x1, bflo(p1.y), fmaf(x2, bflo(p2.y), fmaf(x3, bflo(p3.y), az))));
        az = fmaf(x4, bflo(p4.y), fmaf(x5, bflo(p5.y), fmaf(x6, bflo(p6.y), fmaf(x7, bflo(p7.y), az))));
        aw = fmaf(x0, bfhi(p0.y), fmaf(x1, bfhi(p1.y), fmaf(x2, bfhi(p2.y), fmaf(x3, bfhi(p3.y), aw))));
        aw = fmaf(x4, bfhi(p4.y), fmaf(x5, bfhi(p5.y), fmaf(x6, bfhi(p6.y), fmaf(x7, bfhi(p7.y), aw))));
    }
    if (e + 3 < end) {
        int s0 = src16[e];
        int s1 = src16[e + 1];
        int s2 = src16[e + 2];
        int s3 = src16[e + 3];
        float t0 = s_src[s0 * 8 + head];
        float t1 = s_src[s1 * 8 + head];
        float t2 = s_src[s2 * 8 + head];
        float t3 = s_src[s3 * 8 + head];
        uint2 p0 = h2[s0 * 32 + hl];
        uint2 p1 = h2[s1 * 32 + hl];
        uint2 p2 = h2[s2 * 32 + hl];
        uint2 p3 = h2[s3 * 32 + hl];
        float v0 = t0 + st; v0 = v0 >= 0.f ? v0 : ALPHA * v0;
        float v1 = t1 + st; v1 = v1 >= 0.f ? v1 : ALPHA * v1;
        float v2 = t2 + st; v2 = v2 >= 0.f ? v2 : ALPHA * v2;
        float v3 = t3 + st; v3 = v3 >= 0.f ? v3 : ALPHA * v3;
        float x0 = __expf(fminf(fmaxf(v0, -20.f), 20.f));
        float x1 = __expf(fminf(fmaxf(v1, -20.f), 20.f));
        float x2 = __expf(fminf(fmaxf(v2, -20.f), 20.f));
        float x3 = __expf(fminf(fmaxf(v3, -20.f), 20.f));
        den += (x0 + x1) + (x2 + x3);
        ax = fmaf(x0, bflo(p0.x), fmaf(x1, bflo(p1.x), fmaf(x2, bflo(p2.x), fmaf(x3, bflo(p3.x), ax))));
        ay = fmaf(x0, bfhi(p0.x), fmaf(x1, bfhi(p1.x), fmaf(x2, bfhi(p2.x), fmaf(x3, bfhi(p3.x), ay))));
        az = fmaf(x0, bflo(p0.y), fmaf(x1, bflo(p1.y), fmaf(x2, bflo(p2.y), fmaf(x3, bflo(p3.y), az))));
        aw = fmaf(x0, bfhi(p0.y), fmaf(x1, bfhi(p1.y), fmaf(x2, bfhi(p2.y), fmaf(x3, bfhi(p3.y), aw))));
        e += 4;
    }
    for (; e < end; e++) {
        int sA = src16[e];
        float ssA = s_src[sA * 8 + head];
        uint2 pA = h2[sA * 32 + hl];
        float vA = ssA + st; vA = vA >= 0.f ? vA : ALPHA * vA;
        float exA = __expf(fminf(fmaxf(vA, -20.f), 20.f));
        den += exA;
        ax = fmaf(exA, bflo(pA.x), ax);
        ay = fmaf(exA, bfhi(pA.x), ay);
        az = fmaf(exA, bflo(pA.y), az);
        aw = fmaf(exA, bfhi(pA.y), aw);
    }
    float r = 1.f / (den + EPSV);
    float4 b = *(const float4*)(bias + c);
    float4 o;
    o.x = fmaf(ax, r, b.x);
    o.y = fmaf(ay, r, b.y);
    o.z = fmaf(az, r, b.z);
    o.w = fmaf(aw, r, b.w);
    *(float4*)(outb + (size_t)n * 128 + c) = o;
}

extern "C" void kernel_launch(void* const* d_in, const int* in_sizes, int n_in,
                              void* d_out, int out_size, void* d_ws, size_t ws_size,
                              hipStream_t stream) {
    const float* x    = (const float*)d_in[0];
    const int*   ei   = (const int*)d_in[1];
    const float* W    = (const float*)d_in[2];
    const float* a    = (const float*)d_in[3];
    const float* bias = (const float*)d_in[4];
    float* outb = (float*)d_out;

    char* ws = (char*)d_ws;
    // layout (bytes):
    ushort* hb        = (ushort*)(ws);                   // 12,800,000
    float* s_src      = (float*)(ws + 12800000);         //  1,600,000
    float* s_tgt      = (float*)(ws + 14400000);         //  1,600,000
    int*   rowptr     = (int*)  (ws + 16000000);         //    200,064
    ushort* src16     = (ushort*)(ws + 16200064);        //  1,600,000
    int*   gcnt       = (int*)  (ws + 17800064);         //      1,024
    ushort* WTb       = (ushort*)(ws + 17902528);        //     32,768
    unsigned* bucketbuf = (unsigned*)(ws + 17935296);    //  3,763,200

    const int* srcA = ei;
    const int* tgtA = ei + N_EDGES;

    hipLaunchKernelGGL(k_wt,    dim3(64),   dim3(256), 0, stream, W, WTb, gcnt);
    hipLaunchKernelGGL(k_mid,   dim3(1173), dim3(256), 0, stream,
                       x, WTb, a, hb, s_src, s_tgt, srcA, tgtA, gcnt, bucketbuf);
    hipLaunchKernelGGL(k_passB, dim3(196),  dim3(512), 0, stream, bucketbuf, gcnt, rowptr, src16);
    hipLaunchKernelGGL(k_fused, dim3(6250), dim3(256), 0, stream, rowptr, src16, s_src, s_tgt, (const unsigned*)hb, bias, outb);
}